// Round 2
// baseline (1094.284 us; speedup 1.0000x reference)
//
#include <hip/hip_runtime.h>
#include <hip/hip_bf16.h>

#define B_    1024
#define C_    896
#define N_    49
#define NN    2401
#define HD    128
#define NH    7
#define CQK   1792      // only q,k rows of W are used
#define KTOP  2160      // int(2401*0.9)
#define SCALE 0.08838834764831845f  // 128^-0.5

typedef short bf16x8 __attribute__((ext_vector_type(8)));
typedef float f32x4  __attribute__((ext_vector_type(4)));
typedef float f32x16 __attribute__((ext_vector_type(16)));

__device__ __forceinline__ unsigned short f2bf(float f) {
  unsigned int u = __builtin_bit_cast(unsigned int, f);
  u += 0x7FFFu + ((u >> 16) & 1u);          // RNE
  return (unsigned short)(u >> 16);
}

// ---------------- kernel 1: W (first 1792 rows) -> bf16 ----------------
__global__ void k_convW(const float* __restrict__ W, unsigned short* __restrict__ Wbf) {
  int i = blockIdx.x * 256 + threadIdx.x;
  if (i < CQK * C_) Wbf[i] = f2bf(W[i]);
}

// ---------------- kernel 2: fused attention, one block per batch ----------------
#define T_STRIDE  904                      // bytes/row = 1808 ≡ 16 (mod 128): quad-spread b128 reads
#define QK_STRIDE 264                      // bytes/row = 528  ≡ 16 (mod 128)
#define LG_STRIDE 52
#define SM_T_OFF  0
#define SM_QK_OFF (49 * T_STRIDE * 2)                  // 88592
#define SM_LG_OFF (SM_QK_OFF + 49 * QK_STRIDE * 2)     // 114464
#define SM_FU_OFF (SM_LG_OFF + 64 * LG_STRIDE * 4)     // 127776
#define SM_TOTAL  (SM_FU_OFF + 49 * LG_STRIDE * 4)     // 137968 (<160K)

// One pass: project heads [H0, H0+NHP) with accumulators in VGPRs (A-frags
// register-cached per 224-wide k-chunk, reused across the NHP heads), then
// per head: QK->LDS, logits, softmax, min-accumulate.
template<int H0, int NHP>
__device__ __forceinline__ void attn_pass(const unsigned short* __restrict__ Wbf,
                                          unsigned short* T, unsigned short* QK,
                                          float* LG, float* FU,
                                          float* __restrict__ fusedg,
                                          int b, int tid) {
  const int wid  = tid >> 6;
  const int lane = tid & 63;
  const int c32  = lane & 31;
  const int kg   = lane >> 5;      // 0/1: k-half of the 16-wide k-step
  const int mw   = wid >> 2;       // 0/1: which 32-row m-tile
  const int nt0  = (wid & 3) * 2;  // n-tile pair: {0,1},{2,3} = Q ; {4,5},{6,7} = K

  int ra = mw * 32 + c32; if (ra > 48) ra = 48;          // clamp pad rows
  const unsigned short* Arow = T + ra * T_STRIDE + kg * 8;

  const int rb0 = (nt0 < 4) ? (nt0 * 32) : (C_ + (nt0 - 4) * 32);  // W row base (add h*HD + c32)

  const f32x16 z16 = {0.f};
  f32x16 acc[NHP][2];
#pragma unroll
  for (int hh = 0; hh < NHP; ++hh) { acc[hh][0] = z16; acc[hh][1] = z16; }

  // ---- projection GEMM: QK[49x256/head] = T[49x896] * W_h^T, 32x32x16 MFMA ----
  for (int kc = 0; kc < C_; kc += 224) {
    bf16x8 a[14];
#pragma unroll
    for (int ks = 0; ks < 14; ++ks)
      a[ks] = *(const bf16x8*)(Arow + kc + ks * 16);
#pragma unroll
    for (int hh = 0; hh < NHP; ++hh) {
      const int h = H0 + hh;
      const unsigned short* bp0 = Wbf + (size_t)(rb0 + h * HD + c32) * C_ + kc + kg * 8;
      const unsigned short* bp1 = bp0 + (size_t)32 * C_;
#pragma unroll
      for (int ks = 0; ks < 14; ++ks) {
        bf16x8 b0 = *(const bf16x8*)(bp0 + ks * 16);
        bf16x8 b1 = *(const bf16x8*)(bp1 + ks * 16);
        acc[hh][0] = __builtin_amdgcn_mfma_f32_32x32x16_bf16(a[ks], b0, acc[hh][0], 0, 0, 0);
        acc[hh][1] = __builtin_amdgcn_mfma_f32_32x32x16_bf16(a[ks], b1, acc[hh][1], 0, 0, 0);
      }
    }
  }

  const int lrow = lane & 15;
  const int lk   = (lane >> 4) * 8;
  const f32x4 z4 = {0.f, 0.f, 0.f, 0.f};

#pragma unroll
  for (int hh = 0; hh < NHP; ++hh) {
    const int h = H0 + hh;
    // ---- QK write: D layout col=lane&31, row=(r&3)+8*(r>>2)+4*(lane>>5) ----
#pragma unroll
    for (int t = 0; t < 2; ++t) {
#pragma unroll
      for (int r = 0; r < 16; ++r) {
        int row = mw * 32 + (r & 3) + 8 * (r >> 2) + 4 * kg;
        if (row < N_)
          QK[row * QK_STRIDE + (nt0 + t) * 32 + c32] = f2bf(acc[hh][t][r]);
      }
    }
    __syncthreads();

    // ---- logits L[49x49] = Q * K^T (16x16x32) ----
    f32x4 acc2[2] = {z4, z4};
    int mt[2], ntt[2], rowA[2], rowB[2];
#pragma unroll
    for (int i = 0; i < 2; ++i) {
      int t = wid * 2 + i; mt[i] = t >> 2; ntt[i] = t & 3;
      int rqa = mt[i] * 16 + lrow;  if (rqa > 48) rqa = 48;
      int rqb = ntt[i] * 16 + lrow; if (rqb > 48) rqb = 48;
      rowA[i] = rqa * QK_STRIDE + lk;
      rowB[i] = rqb * QK_STRIDE + HD + lk;
    }
    for (int e0 = 0; e0 < HD; e0 += 32) {
#pragma unroll
      for (int i = 0; i < 2; ++i) {
        bf16x8 aa = *(const bf16x8*)(QK + rowA[i] + e0);
        bf16x8 bb = *(const bf16x8*)(QK + rowB[i] + e0);
        acc2[i] = __builtin_amdgcn_mfma_f32_16x16x32_bf16(aa, bb, acc2[i], 0, 0, 0);
      }
    }
#pragma unroll
    for (int i = 0; i < 2; ++i)
#pragma unroll
      for (int r = 0; r < 4; ++r) {
        int row = mt[i] * 16 + (lane >> 4) * 4 + r;
        int col = ntt[i] * 16 + lrow;
        if (col < N_) LG[row * LG_STRIDE + col] = acc2[i][r] * SCALE;
      }
    __syncthreads();

    // ---- softmax rows + min-over-heads accumulate ----
    for (int r = wid; r < N_; r += 8) {
      float v = (lane < N_) ? LG[r * LG_STRIDE + lane] : -1e30f;
      float mx = v;
#pragma unroll
      for (int off = 32; off >= 1; off >>= 1) mx = fmaxf(mx, __shfl_xor(mx, off));
      float e = (lane < N_) ? __expf(v - mx) : 0.f;
      float s = e;
#pragma unroll
      for (int off = 32; off >= 1; off >>= 1) s += __shfl_xor(s, off);
      float p = e / s;
      if (lane < N_) {
        float cur = (h == 0) ? p : fminf(FU[r * LG_STRIDE + lane], p);
        if (h < NH - 1) FU[r * LG_STRIDE + lane] = cur;
        else            fusedg[(size_t)b * NN + r * N_ + lane] = cur;
      }
    }
    __syncthreads();
  }
}

__global__ __launch_bounds__(512, 1) void k_attn(const float* __restrict__ x,
                                                 const unsigned short* __restrict__ Wbf,
                                                 float* __restrict__ fusedg) {
  extern __shared__ char smem[];
  unsigned short* T  = (unsigned short*)(smem + SM_T_OFF);   // [49][904] tokens bf16
  unsigned short* QK = (unsigned short*)(smem + SM_QK_OFF);  // [49][264] q|k bf16
  float*          LG = (float*)(smem + SM_LG_OFF);           // [64][52] logits
  float*          FU = (float*)(smem + SM_FU_OFF);           // [49][52] min-over-heads

  const int b   = blockIdx.x;
  const int tid = threadIdx.x;

  // stage tokens transposed as packed b64: T[n][4cq..4cq+3] = x[b][4cq..][n]
  const float* xb = x + (size_t)b * (C_ * N_);
  const int CQ = C_ / 4;  // 224
  for (int idx = tid; idx < CQ * N_; idx += 512) {
    int cq = idx / N_;
    int n  = idx - cq * N_;
    const float* xp = xb + (size_t)(4 * cq) * N_ + n;
    float f0 = xp[0], f1 = xp[N_], f2 = xp[2 * N_], f3 = xp[3 * N_];
    unsigned long long pk = (unsigned long long)f2bf(f0)
                          | ((unsigned long long)f2bf(f1) << 16)
                          | ((unsigned long long)f2bf(f2) << 32)
                          | ((unsigned long long)f2bf(f3) << 48);
    *(unsigned long long*)(T + n * T_STRIDE + 4 * cq) = pk;
  }
  __syncthreads();

  attn_pass<0, 4>(Wbf, T, QK, LG, FU, fusedg, b, tid);
  attn_pass<4, 3>(Wbf, T, QK, LG, FU, fusedg, b, tid);
}

// ---------------- kernel 3: per-batch bottom-2160 threshold + union mask ----------------
__global__ void k_select(const float* __restrict__ fusedg, unsigned int* __restrict__ gmask) {
  __shared__ unsigned int v[NN];
  __shared__ unsigned int lmask[76];
  __shared__ int cnt;
  const int b = blockIdx.x, t = threadIdx.x;
  for (int p = t; p < NN; p += 256)
    v[p] = __builtin_bit_cast(unsigned int, fusedg[(size_t)b * NN + p]);
  for (int p = t; p < 76; p += 256) lmask[p] = 0u;
  __syncthreads();

  // binary search on bits: largest u with count(v < u) < KTOP  => member iff v <= u
  unsigned int u = 0;
  for (int bit = 30; bit >= 0; --bit) {
    unsigned int cand = u | (1u << bit);
    if (t == 0) cnt = 0;
    __syncthreads();
    int c = 0;
    for (int p = t; p < NN; p += 256) c += (v[p] < cand) ? 1 : 0;
    atomicAdd(&cnt, c);
    __syncthreads();
    if (cnt < KTOP) u = cand;
    __syncthreads();
  }
  for (int p = t; p < NN; p += 256)
    if (p != 0 && v[p] <= u) atomicOr(&lmask[p >> 5], 1u << (p & 31));
  __syncthreads();
  for (int p = t; p < 76; p += 256)
    if (lmask[p]) atomicOr(&gmask[p], lmask[p]);
}

// ---------------- kernel 4: apply union mask to batch 0 only ----------------
__global__ void k_mask0(float* __restrict__ fusedg, const unsigned int* __restrict__ gmask) {
  for (int p = threadIdx.x; p < NN; p += 256)
    if ((gmask[p >> 5] >> (p & 31)) & 1u) fusedg[p] = 0.f;
}

// ---------------- kernel 5: rollout collapses to row/col sums ----------------
__global__ void k_rollout(const float* __restrict__ fusedg, float* __restrict__ att) {
  __shared__ float fl[NN];
  const int b = blockIdx.x, t = threadIdx.x;
  for (int p = t; p < NN; p += 256) fl[p] = fusedg[(size_t)b * NN + p];
  __syncthreads();
  if (t < N_) {
    float rs = 0.f, cs = 0.f;
    for (int m = 0; m < N_; ++m) { rs += fl[t * N_ + m]; cs += fl[m * N_ + t]; }
    att[b * N_ + t] = (cs + 1.0f) / (49.0f * (rs + 1.0f));
  }
}

// ---------------- kernel 6: rx = x * (1 + att[b,n]) ----------------
__global__ void k_rx(const float* __restrict__ x, const float* __restrict__ att,
                     float* __restrict__ out) {
  const long total4 = (long)B_ * C_ * N_ / 4;
  for (long g = (long)blockIdx.x * 256 + threadIdx.x; g < total4; g += (long)gridDim.x * 256) {
    long e0 = g * 4;
    int b = (int)(e0 / (C_ * N_));
    int r = (int)(e0 - (long)b * (C_ * N_));
    int n = r % N_;
    const float4 xv = ((const float4*)x)[g];
    const float* ab = att + b * N_;
    float a0 = ab[n];
    int n1 = n + 1;  if (n1 == N_) n1 = 0;  float a1 = ab[n1];
    int n2 = n1 + 1; if (n2 == N_) n2 = 0;  float a2 = ab[n2];
    int n3 = n2 + 1; if (n3 == N_) n3 = 0;  float a3 = ab[n3];
    float4 o;
    o.x = xv.x * (1.f + a0); o.y = xv.y * (1.f + a1);
    o.z = xv.z * (1.f + a2); o.w = xv.w * (1.f + a3);
    ((float4*)out)[g] = o;
  }
}

extern "C" void kernel_launch(void* const* d_in, const int* in_sizes, int n_in,
                              void* d_out, int out_size, void* d_ws, size_t ws_size,
                              hipStream_t stream) {
  const float* x = (const float*)d_in[0];
  const float* W = (const float*)d_in[1];
  float* out = (float*)d_out;
  char* ws = (char*)d_ws;

  float*          fused = (float*)ws;                        //  9,834,496 B
  float*          att   = (float*)(ws + 9834496);            //    200,704 B
  unsigned short* Wbf   = (unsigned short*)(ws + 10035200);  //  3,211,264 B
  unsigned int*   gmask = (unsigned int*)(ws + 13246464);    //        304 B

  hipMemsetAsync(gmask, 0, 76 * sizeof(unsigned int), stream);
  k_convW<<<(CQK * C_ + 255) / 256, 256, 0, stream>>>(W, Wbf);

  hipFuncSetAttribute((const void*)k_attn, hipFuncAttributeMaxDynamicSharedMemorySize, SM_TOTAL);
  k_attn<<<B_, 512, SM_TOTAL, stream>>>(x, Wbf, fused);

  k_select<<<B_, 256, 0, stream>>>(fused, gmask);
  k_mask0<<<1, 256, 0, stream>>>(fused, gmask);
  k_rollout<<<B_, 256, 0, stream>>>(fused, att);
  k_rx<<<2048, 256, 0, stream>>>(x, att, out);
}

// Round 3
// 716.830 us; speedup vs baseline: 1.5266x; 1.5266x over previous
//
#include <hip/hip_runtime.h>
#include <hip/hip_bf16.h>

#define B_    1024
#define C_    896
#define N_    49
#define NN    2401
#define HD    128
#define NH    7
#define CQK   1792      // only q,k rows of W are used
#define KTOP  2160      // int(2401*0.9)
#define SCALE 0.08838834764831845f  // 128^-0.5

typedef short bf16x8 __attribute__((ext_vector_type(8)));
typedef float f32x4  __attribute__((ext_vector_type(4)));

__device__ __forceinline__ unsigned short f2bf(float f) {
  unsigned int u = __builtin_bit_cast(unsigned int, f);
  u += 0x7FFFu + ((u >> 16) & 1u);          // RNE
  return (unsigned short)(u >> 16);
}

// ---------------- kernel 1: W (first 1792 rows) -> bf16 ----------------
__global__ void k_convW(const float* __restrict__ W, unsigned short* __restrict__ Wbf) {
  int i = blockIdx.x * 256 + threadIdx.x;
  if (i < CQK * C_) Wbf[i] = f2bf(W[i]);
}

// ---------------- kernel 2: fused attention, one block per batch ----------------
// 1024 threads = 16 waves = 4 waves/SIMD (vs round-1's 2). LDS 141,120 B.
// Projection: 16 waves = 8 n-groups x 2 k-halves, each wave (4m x 2n),
// partial QK (bf16) per k-half. Logits use MFMA bilinearity over partials.
#define T_STRIDE   904   // 1808 B/row = 452 dw = 4 mod 32 -> b128 rows 2-way free
#define QKP_STRIDE 268   // 536 B/row = 134 dw = 6 mod 32 -> writes conflict-free
#define SM_QKP_OFF (49 * T_STRIDE * 2)                 // 88592
#define SM_TOTAL   (SM_QKP_OFF + 2 * 49 * QKP_STRIDE * 2)  // 141120 (<160K)

__global__ __launch_bounds__(1024, 4) void k_attn(const float* __restrict__ x,
                                                  const unsigned short* __restrict__ Wbf,
                                                  float* __restrict__ fusedg) {
  extern __shared__ char smem[];
  unsigned short* T    = (unsigned short*)smem;                 // [49][904] tokens bf16
  unsigned short* QKP0 = (unsigned short*)(smem + SM_QKP_OFF);  // [49][268] k-half-0 partial
  unsigned short* QKP1 = QKP0 + 49 * QKP_STRIDE;                // [49][268] k-half-1 partial

  const int b    = blockIdx.x;
  const int tid  = threadIdx.x;
  const int wid  = tid >> 6;
  const int lane = tid & 63;
  const int lrow = lane & 15;
  const int hi   = lane >> 4;
  const int lk   = hi * 8;
  const int kh   = wid & 1;   // k-half: 0 -> c 0..447, 1 -> c 448..895
  const int ng   = wid >> 1;  // n-group 0..7 (2 n-tiles of 16 each); 0-3 = Q, 4-7 = K

  // ---- stage tokens transposed as packed b64: T[n][4cq..] = x[b][4cq..][n] ----
  const float* xb = x + (size_t)b * (C_ * N_);
  for (int idx = tid; idx < (C_ / 4) * N_; idx += 1024) {
    int cq = idx / N_;
    int n  = idx - cq * N_;
    const float* xp = xb + (size_t)(4 * cq) * N_ + n;
    float f0 = xp[0], f1 = xp[N_], f2 = xp[2 * N_], f3 = xp[3 * N_];
    unsigned long long pk = (unsigned long long)f2bf(f0)
                          | ((unsigned long long)f2bf(f1) << 16)
                          | ((unsigned long long)f2bf(f2) << 32)
                          | ((unsigned long long)f2bf(f3) << 48);
    *(unsigned long long*)(T + n * T_STRIDE + 4 * cq) = pk;
  }
  __syncthreads();

  // A-fragment row bases (clamp pad rows; results discarded by write guards)
  int rA[4];
#pragma unroll
  for (int m = 0; m < 4; ++m) {
    int r = 16 * m + lrow; if (r > 48) r = 48;
    rA[m] = r * T_STRIDE + kh * 448 + lk;
  }
  unsigned short* QKPmy = kh ? QKP1 : QKP0;
  const f32x4 z4 = {0.f, 0.f, 0.f, 0.f};

  float fu[16];  // per-lane running min over heads (logits waves only)

  for (int h = 0; h < NH; ++h) {
    // ---- projection partial: QKPmy[49x256] += T[:, kh-half] * W^T ----
    f32x4 acc[4][2];
#pragma unroll
    for (int m = 0; m < 4; ++m) { acc[m][0] = z4; acc[m][1] = z4; }

    const unsigned short* wp[2];
#pragma unroll
    for (int t = 0; t < 2; ++t) {
      int nt = ng * 2 + t;
      int wr = (nt < 8) ? (h * HD + nt * 16 + lrow)
                        : (C_ + h * HD + (nt - 8) * 16 + lrow);
      wp[t] = Wbf + (size_t)wr * C_ + kh * 448 + lk;
    }
#pragma unroll
    for (int ks = 0; ks < 14; ++ks) {
      bf16x8 a[4], bb[2];
#pragma unroll
      for (int m = 0; m < 4; ++m) a[m] = *(const bf16x8*)(T + rA[m] + ks * 32);
#pragma unroll
      for (int t = 0; t < 2; ++t) bb[t] = *(const bf16x8*)(wp[t] + ks * 32);
#pragma unroll
      for (int m = 0; m < 4; ++m)
#pragma unroll
        for (int t = 0; t < 2; ++t)
          acc[m][t] = __builtin_amdgcn_mfma_f32_16x16x32_bf16(a[m], bb[t], acc[m][t], 0, 0, 0);
    }
    if (ng < 4) {  // fold softmax scale into Q (both partials: linear)
#pragma unroll
      for (int m = 0; m < 4; ++m)
#pragma unroll
        for (int t = 0; t < 2; ++t)
#pragma unroll
          for (int r = 0; r < 4; ++r) acc[m][t][r] *= SCALE;
    }
#pragma unroll
    for (int m = 0; m < 4; ++m)
#pragma unroll
      for (int t = 0; t < 2; ++t)
#pragma unroll
        for (int r = 0; r < 4; ++r) {
          int row = m * 16 + hi * 4 + r;
          if (row < N_)
            QKPmy[row * QKP_STRIDE + (ng * 2 + t) * 16 + lrow] = f2bf(acc[m][t][r]);
        }
    __syncthreads();

    // ---- logits + in-register softmax + min (waves 0-3; D[k][q] swapped) ----
    if (wid < 4) {
      f32x4 acc2[4] = {z4, z4, z4, z4};
      int qrow = wid * 16 + lrow; if (qrow > 48) qrow = 48;
#pragma unroll
      for (int e = 0; e < 4; ++e) {
        bf16x8 q0 = *(const bf16x8*)(QKP0 + qrow * QKP_STRIDE + e * 32 + lk);
        bf16x8 q1 = *(const bf16x8*)(QKP1 + qrow * QKP_STRIDE + e * 32 + lk);
#pragma unroll
        for (int kt = 0; kt < 4; ++kt) {
          int krow = kt * 16 + lrow; if (krow > 48) krow = 48;
          bf16x8 k0 = *(const bf16x8*)(QKP0 + krow * QKP_STRIDE + HD + e * 32 + lk);
          bf16x8 k1 = *(const bf16x8*)(QKP1 + krow * QKP_STRIDE + HD + e * 32 + lk);
          // (Qp0+Qp1)·(Kp0+Kp1)^T via bilinearity: 4 MFMAs, no VALU adds
          acc2[kt] = __builtin_amdgcn_mfma_f32_16x16x32_bf16(k1, q1, acc2[kt], 0, 0, 0);
          acc2[kt] = __builtin_amdgcn_mfma_f32_16x16x32_bf16(k1, q0, acc2[kt], 0, 0, 0);
          acc2[kt] = __builtin_amdgcn_mfma_f32_16x16x32_bf16(k0, q1, acc2[kt], 0, 0, 0);
          acc2[kt] = __builtin_amdgcn_mfma_f32_16x16x32_bf16(k0, q0, acc2[kt], 0, 0, 0);
        }
      }
      // per-lane: 16 logit entries (k = kt*16 + hi*4 + r) for q-col = wid*16+lrow
      float mx = -1e30f;
#pragma unroll
      for (int kt = 0; kt < 4; ++kt)
#pragma unroll
        for (int r = 0; r < 4; ++r) {
          int k = kt * 16 + hi * 4 + r;
          if (k < N_) mx = fmaxf(mx, acc2[kt][r]);
        }
      mx = fmaxf(mx, __shfl_xor(mx, 16));
      mx = fmaxf(mx, __shfl_xor(mx, 32));
      float ev[16];
      float sum = 0.f;
#pragma unroll
      for (int kt = 0; kt < 4; ++kt)
#pragma unroll
        for (int r = 0; r < 4; ++r) {
          int k = kt * 16 + hi * 4 + r;
          float e = (k < N_) ? __expf(acc2[kt][r] - mx) : 0.f;
          ev[kt * 4 + r] = e;
          sum += e;
        }
      sum += __shfl_xor(sum, 16);
      sum += __shfl_xor(sum, 32);
      float rs = 1.0f / sum;
#pragma unroll
      for (int i = 0; i < 16; ++i) {
        float p = ev[i] * rs;
        fu[i] = (h == 0) ? p : fminf(fu[i], p);
      }
      if (h == NH - 1) {
        int q = wid * 16 + lrow;
        if (q < N_) {
#pragma unroll
          for (int kt = 0; kt < 4; ++kt)
#pragma unroll
            for (int r = 0; r < 4; ++r) {
              int k = kt * 16 + hi * 4 + r;
              if (k < N_) fusedg[(size_t)b * NN + q * N_ + k] = fu[kt * 4 + r];
            }
        }
      }
    }
    __syncthreads();
  }
}

// ---------------- kernel 3: per-batch bottom-2160 threshold + union mask ----------------
__global__ void k_select(const float* __restrict__ fusedg, unsigned int* __restrict__ gmask) {
  __shared__ unsigned int v[NN];
  __shared__ unsigned int lmask[76];
  __shared__ int cnt;
  const int b = blockIdx.x, t = threadIdx.x;
  for (int p = t; p < NN; p += 256)
    v[p] = __builtin_bit_cast(unsigned int, fusedg[(size_t)b * NN + p]);
  for (int p = t; p < 76; p += 256) lmask[p] = 0u;
  __syncthreads();

  // binary search on bits: largest u with count(v < u) < KTOP  => member iff v <= u
  unsigned int u = 0;
  for (int bit = 30; bit >= 0; --bit) {
    unsigned int cand = u | (1u << bit);
    if (t == 0) cnt = 0;
    __syncthreads();
    int c = 0;
    for (int p = t; p < NN; p += 256) c += (v[p] < cand) ? 1 : 0;
    atomicAdd(&cnt, c);
    __syncthreads();
    if (cnt < KTOP) u = cand;
    __syncthreads();
  }
  for (int p = t; p < NN; p += 256)
    if (p != 0 && v[p] <= u) atomicOr(&lmask[p >> 5], 1u << (p & 31));
  __syncthreads();
  for (int p = t; p < 76; p += 256)
    if (lmask[p]) atomicOr(&gmask[p], lmask[p]);
}

// ---------------- kernel 4: apply union mask to batch 0 only ----------------
__global__ void k_mask0(float* __restrict__ fusedg, const unsigned int* __restrict__ gmask) {
  for (int p = threadIdx.x; p < NN; p += 256)
    if ((gmask[p >> 5] >> (p & 31)) & 1u) fusedg[p] = 0.f;
}

// ---------------- kernel 5: rollout collapses to row/col sums ----------------
__global__ void k_rollout(const float* __restrict__ fusedg, float* __restrict__ att) {
  __shared__ float fl[NN];
  const int b = blockIdx.x, t = threadIdx.x;
  for (int p = t; p < NN; p += 256) fl[p] = fusedg[(size_t)b * NN + p];
  __syncthreads();
  if (t < N_) {
    float rs = 0.f, cs = 0.f;
    for (int m = 0; m < N_; ++m) { rs += fl[t * N_ + m]; cs += fl[m * N_ + t]; }
    att[b * N_ + t] = (cs + 1.0f) / (49.0f * (rs + 1.0f));
  }
}

// ---------------- kernel 6: rx = x * (1 + att[b,n]) ----------------
__global__ void k_rx(const float* __restrict__ x, const float* __restrict__ att,
                     float* __restrict__ out) {
  const long total4 = (long)B_ * C_ * N_ / 4;
  for (long g = (long)blockIdx.x * 256 + threadIdx.x; g < total4; g += (long)gridDim.x * 256) {
    long e0 = g * 4;
    int b = (int)(e0 / (C_ * N_));
    int r = (int)(e0 - (long)b * (C_ * N_));
    int n = r % N_;
    const float4 xv = ((const float4*)x)[g];
    const float* ab = att + b * N_;
    float a0 = ab[n];
    int n1 = n + 1;  if (n1 == N_) n1 = 0;  float a1 = ab[n1];
    int n2 = n1 + 1; if (n2 == N_) n2 = 0;  float a2 = ab[n2];
    int n3 = n2 + 1; if (n3 == N_) n3 = 0;  float a3 = ab[n3];
    float4 o;
    o.x = xv.x * (1.f + a0); o.y = xv.y * (1.f + a1);
    o.z = xv.z * (1.f + a2); o.w = xv.w * (1.f + a3);
    ((float4*)out)[g] = o;
  }
}

extern "C" void kernel_launch(void* const* d_in, const int* in_sizes, int n_in,
                              void* d_out, int out_size, void* d_ws, size_t ws_size,
                              hipStream_t stream) {
  const float* x = (const float*)d_in[0];
  const float* W = (const float*)d_in[1];
  float* out = (float*)d_out;
  char* ws = (char*)d_ws;

  float*          fused = (float*)ws;                        //  9,834,496 B
  float*          att   = (float*)(ws + 9834496);            //    200,704 B
  unsigned short* Wbf   = (unsigned short*)(ws + 10035200);  //  3,211,264 B
  unsigned int*   gmask = (unsigned int*)(ws + 13246464);    //        304 B

  hipMemsetAsync(gmask, 0, 76 * sizeof(unsigned int), stream);
  k_convW<<<(CQK * C_ + 255) / 256, 256, 0, stream>>>(W, Wbf);

  hipFuncSetAttribute((const void*)k_attn, hipFuncAttributeMaxDynamicSharedMemorySize, SM_TOTAL);
  k_attn<<<B_, 1024, SM_TOTAL, stream>>>(x, Wbf, fused);

  k_select<<<B_, 256, 0, stream>>>(fused, gmask);
  k_mask0<<<1, 256, 0, stream>>>(fused, gmask);
  k_rollout<<<B_, 256, 0, stream>>>(fused, att);
  k_rx<<<2048, 256, 0, stream>>>(x, att, out);
}

// Round 4
// 537.721 us; speedup vs baseline: 2.0350x; 1.3331x over previous
//
#include <hip/hip_runtime.h>
#include <hip/hip_bf16.h>

#define B_    1024
#define C_    896
#define N_    49
#define NN    2401
#define HD    128
#define NH    7
#define CQK   1792      // q,k rows of W (V never used)
#define KTOP  2160      // int(2401*0.9)
#define SCALE 0.08838834764831845f  // 128^-0.5

typedef unsigned short ushort_t;
typedef unsigned int u32;
typedef short bf16x8 __attribute__((ext_vector_type(8)));
typedef float f32x4  __attribute__((ext_vector_type(4)));

__device__ __forceinline__ ushort_t f2bf(float f) {
  u32 u = __builtin_bit_cast(u32, f);
  u += 0x7FFFu + ((u >> 16) & 1u);          // RNE
  return (ushort_t)(u >> 16);
}

__device__ __forceinline__ void gload16(const ushort_t* g, ushort_t* l) {
  __builtin_amdgcn_global_load_lds((const __attribute__((address_space(1))) u32*)g,
                                   (__attribute__((address_space(3))) u32*)l, 16, 0, 0);
}

// ---------------- kernel 1: W (first 1792 rows) -> bf16 ----------------
__global__ void k_convW(const float* __restrict__ W, ushort_t* __restrict__ Wbf) {
  int i = blockIdx.x * 256 + threadIdx.x;
  if (i < CQK * C_) Wbf[i] = f2bf(W[i]);
}

// ---------------- kernel 2: transpose x -> tokens bf16 [MG][896] ----------------
// block = (batch, c-group of 64). Reads coalesced along n, writes coalesced along c.
__global__ __launch_bounds__(256) void k_tr(const float* __restrict__ x,
                                            ushort_t* __restrict__ tokens,
                                            int boff) {
  __shared__ ushort_t T2[49][72];
  const int bid = blockIdx.x;
  const int bl  = bid / 14;            // local batch
  const int cg  = bid % 14;            // c-group (64 channels)
  const float* xb = x + (size_t)(boff + bl) * (C_ * N_) + (size_t)cg * 64 * N_;
  for (int idx = threadIdx.x; idx < 64 * 49; idx += 256) {
    int ci = idx / 49, n = idx - ci * 49;
    T2[n][ci] = f2bf(xb[ci * 49 + n]);
  }
  __syncthreads();
  ushort_t* tb = tokens + (size_t)(bl * 49) * C_ + cg * 64;
  for (int idx = threadIdx.x; idx < 49 * 8; idx += 256) {
    int n = idx >> 3, ch = idx & 7;
    *(bf16x8*)(tb + (size_t)n * C_ + ch * 8) = *(const bf16x8*)&T2[n][ch * 8];
  }
}

// ---------------- kernel 3: GEMM QK[MG][1792] = tokens[MG][896] * Wbf^T ----------------
// m97 structure: 128x128 tile, BK=32, 4 waves (2x2), global_load_lds x16, dbuf LDS.
__device__ __forceinline__ void stage_tile(const ushort_t* __restrict__ tokens,
                                           const ushort_t* __restrict__ Wbf,
                                           ushort_t (*sA)[4096], ushort_t (*sB)[4096],
                                           int buf, int k0, int m0, int n0, int MG,
                                           int w, int l) {
#pragma unroll
  for (int j = 0; j < 2; ++j) {
    int row = (w * 2 + j) * 16 + (l >> 2);
    int kp  = (l & 3) * 8;
    int srow = m0 + row; if (srow >= MG) srow = MG - 1;
    gload16(tokens + (size_t)srow * C_ + k0 + kp, &sA[buf][(w * 2 + j) * 512]);
    gload16(Wbf + (size_t)(n0 + row) * C_ + k0 + kp, &sB[buf][(w * 2 + j) * 512]);
  }
}

__global__ __launch_bounds__(256, 3) void k_gemm(const ushort_t* __restrict__ tokens,
                                                 const ushort_t* __restrict__ Wbf,
                                                 ushort_t* __restrict__ QK,
                                                 int MG) {
  __shared__ ushort_t sA[2][4096], sB[2][4096];

  // bijective XCD-chunk swizzle (m204)
  const int nwg = gridDim.x;
  const int q8 = nwg >> 3, r8 = nwg & 7;
  const int xcd = blockIdx.x & 7, idx8 = blockIdx.x >> 3;
  const int tile = (xcd < r8 ? xcd * (q8 + 1) : r8 * (q8 + 1) + (xcd - r8) * q8) + idx8;

  const int mt = tile / 14, nt = tile - mt * 14;
  const int m0 = mt * 128, n0 = nt * 128;

  const int tid = threadIdx.x;
  const int w = tid >> 6, l = tid & 63;
  const int lane = l;
  const int lrow = lane & 15, hi = lane >> 4;
  const int mw = w & 1, nw = w >> 1;

  f32x4 acc[4][4];
#pragma unroll
  for (int m = 0; m < 4; ++m)
#pragma unroll
    for (int n = 0; n < 4; ++n) acc[m][n] = (f32x4){0.f, 0.f, 0.f, 0.f};

  stage_tile(tokens, Wbf, sA, sB, 0, 0, m0, n0, MG, w, l);
  __syncthreads();

  for (int kt = 0; kt < 28; ++kt) {
    const int buf = kt & 1;
    if (kt + 1 < 28)
      stage_tile(tokens, Wbf, sA, sB, buf ^ 1, (kt + 1) * 32, m0, n0, MG, w, l);
    bf16x8 a[4], bb[4];
#pragma unroll
    for (int m = 0; m < 4; ++m)
      a[m] = *(const bf16x8*)&sA[buf][(mw * 64 + m * 16 + lrow) * 32 + hi * 8];
#pragma unroll
    for (int n = 0; n < 4; ++n)
      bb[n] = *(const bf16x8*)&sB[buf][(nw * 64 + n * 16 + lrow) * 32 + hi * 8];
#pragma unroll
    for (int m = 0; m < 4; ++m)
#pragma unroll
      for (int n = 0; n < 4; ++n)
        acc[m][n] = __builtin_amdgcn_mfma_f32_16x16x32_bf16(a[m], bb[n], acc[m][n], 0, 0, 0);
    __syncthreads();
  }

  // epilogue: D col=lane&15, row=(lane>>4)*4+r; fold SCALE into Q cols (<896)
#pragma unroll
  for (int m = 0; m < 4; ++m) {
#pragma unroll
    for (int n = 0; n < 4; ++n) {
      int gcol = n0 + nw * 64 + n * 16 + lrow;
      float sc = (gcol < C_) ? SCALE : 1.0f;
#pragma unroll
      for (int r = 0; r < 4; ++r) {
        int grow = m0 + mw * 64 + m * 16 + hi * 4 + r;
        if (grow < MG)
          QK[(size_t)grow * CQK + gcol] = f2bf(acc[m][n][r] * sc);
      }
    }
  }
}

// ---------------- kernel 4: per-batch logits + softmax + min (in-register) ----------------
__global__ __launch_bounds__(256) void k_attn2(const ushort_t* __restrict__ QK,
                                               float* __restrict__ fusedg,
                                               int boff) {
  const int bl   = blockIdx.x;
  const int tid  = threadIdx.x;
  const int wid  = tid >> 6;
  const int lane = tid & 63;
  const int lrow = lane & 15;
  const int hi   = lane >> 4;
  const int lk   = hi * 8;
  const f32x4 z4 = {0.f, 0.f, 0.f, 0.f};

  int qrow = wid * 16 + lrow; if (qrow > 48) qrow = 48;
  const ushort_t* Qrow = QK + (size_t)(bl * 49 + qrow) * CQK;

  float fu[16];

  for (int h = 0; h < NH; ++h) {
    f32x4 acc2[4] = {z4, z4, z4, z4};
#pragma unroll
    for (int e = 0; e < 4; ++e) {
      bf16x8 qf = *(const bf16x8*)(Qrow + h * HD + e * 32 + lk);
#pragma unroll
      for (int kt = 0; kt < 4; ++kt) {
        int krow = kt * 16 + lrow; if (krow > 48) krow = 48;
        bf16x8 kf = *(const bf16x8*)(QK + (size_t)(bl * 49 + krow) * CQK
                                     + C_ + h * HD + e * 32 + lk);
        acc2[kt] = __builtin_amdgcn_mfma_f32_16x16x32_bf16(kf, qf, acc2[kt], 0, 0, 0);
      }
    }
    // per-lane: 16 logits (k = kt*16 + hi*4 + r) for q-col = wid*16+lrow
    float mx = -1e30f;
#pragma unroll
    for (int kt = 0; kt < 4; ++kt)
#pragma unroll
      for (int r = 0; r < 4; ++r) {
        int k = kt * 16 + hi * 4 + r;
        if (k < N_) mx = fmaxf(mx, acc2[kt][r]);
      }
    mx = fmaxf(mx, __shfl_xor(mx, 16));
    mx = fmaxf(mx, __shfl_xor(mx, 32));
    float ev[16];
    float sum = 0.f;
#pragma unroll
    for (int kt = 0; kt < 4; ++kt)
#pragma unroll
      for (int r = 0; r < 4; ++r) {
        int k = kt * 16 + hi * 4 + r;
        float e = (k < N_) ? __expf(acc2[kt][r] - mx) : 0.f;
        ev[kt * 4 + r] = e;
        sum += e;
      }
    sum += __shfl_xor(sum, 16);
    sum += __shfl_xor(sum, 32);
    float rs = 1.0f / sum;
#pragma unroll
    for (int i = 0; i < 16; ++i) {
      float p = ev[i] * rs;
      fu[i] = (h == 0) ? p : fminf(fu[i], p);
    }
    if (h == NH - 1) {
      int q = wid * 16 + lrow;
      if (q < N_) {
#pragma unroll
        for (int kt = 0; kt < 4; ++kt)
#pragma unroll
          for (int r = 0; r < 4; ++r) {
            int k = kt * 16 + hi * 4 + r;
            if (k < N_)
              fusedg[(size_t)(boff + bl) * NN + q * N_ + k] = fu[kt * 4 + r];
          }
      }
    }
  }
}

// ---------------- kernel 5: per-batch bottom-2160 threshold + union mask ----------------
__global__ void k_select(const float* __restrict__ fusedg, u32* __restrict__ gmask) {
  __shared__ u32 v[NN];
  __shared__ u32 lmask[76];
  __shared__ int cnt;
  const int b = blockIdx.x, t = threadIdx.x;
  for (int p = t; p < NN; p += 256)
    v[p] = __builtin_bit_cast(u32, fusedg[(size_t)b * NN + p]);
  for (int p = t; p < 76; p += 256) lmask[p] = 0u;
  __syncthreads();
  u32 u = 0;
  for (int bit = 30; bit >= 0; --bit) {
    u32 cand = u | (1u << bit);
    if (t == 0) cnt = 0;
    __syncthreads();
    int c = 0;
    for (int p = t; p < NN; p += 256) c += (v[p] < cand) ? 1 : 0;
    atomicAdd(&cnt, c);
    __syncthreads();
    if (cnt < KTOP) u = cand;
    __syncthreads();
  }
  for (int p = t; p < NN; p += 256)
    if (p != 0 && v[p] <= u) atomicOr(&lmask[p >> 5], 1u << (p & 31));
  __syncthreads();
  for (int p = t; p < 76; p += 256)
    if (lmask[p]) atomicOr(&gmask[p], lmask[p]);
}

// ---------------- kernel 6: apply union mask to batch 0 only ----------------
__global__ void k_mask0(float* __restrict__ fusedg, const u32* __restrict__ gmask) {
  for (int p = threadIdx.x; p < NN; p += 256)
    if ((gmask[p >> 5] >> (p & 31)) & 1u) fusedg[p] = 0.f;
}

// ---------------- kernel 7: rollout -> att ----------------
__global__ void k_rollout(const float* __restrict__ fusedg, float* __restrict__ att) {
  __shared__ float fl[NN];
  const int b = blockIdx.x, t = threadIdx.x;
  for (int p = t; p < NN; p += 256) fl[p] = fusedg[(size_t)b * NN + p];
  __syncthreads();
  if (t < N_) {
    float rs = 0.f, cs = 0.f;
    for (int m = 0; m < N_; ++m) { rs += fl[t * N_ + m]; cs += fl[m * N_ + t]; }
    att[b * N_ + t] = (cs + 1.0f) / (49.0f * (rs + 1.0f));
  }
}

// ---------------- kernel 8: rx = x * (1 + att[b,n]) ----------------
__global__ void k_rx(const float* __restrict__ x, const float* __restrict__ att,
                     float* __restrict__ out) {
  const long total4 = (long)B_ * C_ * N_ / 4;
  for (long g = (long)blockIdx.x * 256 + threadIdx.x; g < total4; g += (long)gridDim.x * 256) {
    long e0 = g * 4;
    int b = (int)(e0 / (C_ * N_));
    int r = (int)(e0 - (long)b * (C_ * N_));
    int n = r % N_;
    const float4 xv = ((const float4*)x)[g];
    const float* ab = att + b * N_;
    float a0 = ab[n];
    int n1 = n + 1;  if (n1 == N_) n1 = 0;  float a1 = ab[n1];
    int n2 = n1 + 1; if (n2 == N_) n2 = 0;  float a2 = ab[n2];
    int n3 = n2 + 1; if (n3 == N_) n3 = 0;  float a3 = ab[n3];
    float4 o;
    o.x = xv.x * (1.f + a0); o.y = xv.y * (1.f + a1);
    o.z = xv.z * (1.f + a2); o.w = xv.w * (1.f + a3);
    ((float4*)out)[g] = o;
  }
}

extern "C" void kernel_launch(void* const* d_in, const int* in_sizes, int n_in,
                              void* d_out, int out_size, void* d_ws, size_t ws_size,
                              hipStream_t stream) {
  const float* x = (const float*)d_in[0];
  const float* W = (const float*)d_in[1];
  float* out = (float*)d_out;
  char* ws = (char*)d_ws;

  // choose group size G (batches per pass) by workspace capacity
  const size_t fixed = 9834496 /*fused*/ + 200704 /*att*/ + 3211264 /*Wbf*/ + 1024 /*gmask*/;
  int G = 32;
  const int cands[6] = {1024, 512, 256, 128, 64, 32};
  for (int i = 0; i < 6; ++i) {
    if (fixed + (size_t)cands[i] * 49 * CQK * 2 <= ws_size) { G = cands[i]; break; }
  }

  const size_t qkbytes = (size_t)G * 49 * CQK * 2;
  ushort_t* QKg   = (ushort_t*)ws;
  float*    fused = (float*)(ws + qkbytes);
  float*    att   = (float*)(ws + qkbytes + 9834496);
  ushort_t* Wbf   = (ushort_t*)(ws + qkbytes + 9834496 + 200704);
  u32*      gmask = (u32*)(ws + qkbytes + 9834496 + 200704 + 3211264);
  ushort_t* tokens = (ushort_t*)d_out;   // scratch; d_out fully rewritten by k_rx

  hipMemsetAsync(gmask, 0, 76 * sizeof(u32), stream);
  k_convW<<<(CQK * C_ + 255) / 256, 256, 0, stream>>>(W, Wbf);

  const int ngroups = B_ / G;
  for (int g = 0; g < ngroups; ++g) {
    const int boff = g * G;
    const int MG = G * 49;
    const int mtc = (MG + 127) / 128;
    k_tr<<<G * 14, 256, 0, stream>>>(x, tokens, boff);
    k_gemm<<<mtc * 14, 256, 0, stream>>>(tokens, Wbf, QKg, MG);
    k_attn2<<<G, 256, 0, stream>>>(QKg, fused, boff);
  }

  k_select<<<B_, 256, 0, stream>>>(fused, gmask);
  k_mask0<<<1, 256, 0, stream>>>(fused, gmask);
  k_rollout<<<B_, 256, 0, stream>>>(fused, att);
  k_rx<<<2048, 256, 0, stream>>>(x, att, out);
}

// Round 5
// 522.642 us; speedup vs baseline: 2.0938x; 1.0289x over previous
//
#include <hip/hip_runtime.h>
#include <hip/hip_bf16.h>

#define B_    1024
#define C_    896
#define N_    49
#define NN    2401
#define HD    128
#define NH    7
#define CQK   1792      // q,k rows of W (V never used)
#define KTOP  2160      // int(2401*0.9)
#define SCALE 0.08838834764831845f  // 128^-0.5

typedef unsigned short ushort_t;
typedef unsigned int u32;
typedef short bf16x8 __attribute__((ext_vector_type(8)));
typedef float f32x4  __attribute__((ext_vector_type(4)));

__device__ __forceinline__ ushort_t f2bf(float f) {
  u32 u = __builtin_bit_cast(u32, f);
  u += 0x7FFFu + ((u >> 16) & 1u);          // RNE
  return (ushort_t)(u >> 16);
}

__device__ __forceinline__ void gload16(const ushort_t* g, ushort_t* l) {
  __builtin_amdgcn_global_load_lds((const __attribute__((address_space(1))) u32*)g,
                                   (__attribute__((address_space(3))) u32*)l, 16, 0, 0);
}

// ---------------- kernel 1: W (first 1792 rows) -> bf16 ----------------
__global__ void k_convW(const float* __restrict__ W, ushort_t* __restrict__ Wbf) {
  int i = blockIdx.x * 256 + threadIdx.x;
  if (i < CQK * C_) Wbf[i] = f2bf(W[i]);
}

// ---------------- kernel 2: transpose x -> tokens bf16 [MG][896] ----------------
__global__ __launch_bounds__(256) void k_tr(const float* __restrict__ x,
                                            ushort_t* __restrict__ tokens,
                                            int boff) {
  __shared__ ushort_t T2[49][72];
  const int bid = blockIdx.x;
  const int bl  = bid / 14;            // local batch
  const int cg  = bid % 14;            // c-group (64 channels)
  const float* xb = x + (size_t)(boff + bl) * (C_ * N_) + (size_t)cg * 64 * N_;
  for (int idx = threadIdx.x; idx < 64 * 49; idx += 256) {
    int ci = idx / 49, n = idx - ci * 49;
    T2[n][ci] = f2bf(xb[ci * 49 + n]);
  }
  __syncthreads();
  ushort_t* tb = tokens + (size_t)(bl * 49) * C_ + cg * 64;
  for (int idx = threadIdx.x; idx < 49 * 8; idx += 256) {
    int n = idx >> 3, ch = idx & 7;
    *(bf16x8*)(tb + (size_t)n * C_ + ch * 8) = *(const bf16x8*)&T2[n][ch * 8];
  }
}

// ---------------- kernel 3: GEMM QK = tokens * Wbf^T, deep-pipelined ----------------
// 256x256 tile, BK=32, 8 waves (2M x 4N), 4-slot LDS ring (128 KB), counted vmcnt,
// raw s_barrier (no drain), st-swizzle: 16B-slot ^= (row>>1)&3 on global source + ds_read.
#define GEMM_LDS 131072

// stage one K-tile (A 16KB + B 16KB) into slot pointers; 4 gload16/thread.
__device__ __forceinline__ void stage(const ushort_t* __restrict__ tok,
                                      const ushort_t* __restrict__ Wb,
                                      ushort_t* sAs, ushort_t* sBs,
                                      int kt, int m0, int n0, int MG, int w, int l) {
  const int k0 = kt * 32;
  const int colel = 8 * ((l & 3) ^ ((l >> 3) & 3));   // pre-swizzled source slot
#pragma unroll
  for (int j = 0; j < 2; ++j) {
    const int row = (w * 2 + j) * 16 + (l >> 2);
    int arow = m0 + row; if (arow >= MG) arow = MG - 1;
    gload16(tok + (size_t)arow * C_ + k0 + colel, sAs + (w * 2 + j) * 512);
    gload16(Wb + (size_t)(n0 + row) * C_ + k0 + colel, sBs + (w * 2 + j) * 512);
  }
}

__global__ __launch_bounds__(512, 2) void k_gemm(const ushort_t* __restrict__ tokens,
                                                 const ushort_t* __restrict__ Wbf,
                                                 ushort_t* __restrict__ QK,
                                                 int MG, int mtc) {
  extern __shared__ ushort_t gsm[];
  ushort_t* sA = gsm;            // [4][256*32]
  ushort_t* sB = gsm + 32768;    // [4][256*32]

  // bijective XCD-chunk swizzle (m204)
  const int nwg = gridDim.x;
  const int q8 = nwg >> 3, r8 = nwg & 7;
  const int xcd = blockIdx.x & 7, idx8 = blockIdx.x >> 3;
  const int tile = (xcd < r8 ? xcd * (q8 + 1) : r8 * (q8 + 1) + (xcd - r8) * q8) + idx8;

  const int mt = tile / 7, nt = tile - mt * 7;
  const int m0 = mt * 256, n0 = nt * 256;

  const int tid = threadIdx.x;
  const int w = tid >> 6, l = tid & 63;
  const int lrow = l & 15, hi = l >> 4;
  const int mw = w & 1, nw = w >> 1;

  // fragment read offsets (elements); slot term added per K-tile
  const int cswz = 8 * (hi ^ ((lrow >> 1) & 3));
  const int aoffb = (mw * 128 + lrow) * 32 + cswz;
  const int boffb = (nw * 64 + lrow) * 32 + cswz;

  f32x4 acc[8][4];
#pragma unroll
  for (int m = 0; m < 8; ++m)
#pragma unroll
    for (int n = 0; n < 4; ++n) acc[m][n] = (f32x4){0.f, 0.f, 0.f, 0.f};

  // prologue: stage tiles 0,1,2 (12 loads in flight), wait for tile 0 (allow 8)
  stage(tokens, Wbf, sA,         sB,         0, m0, n0, MG, w, l);
  stage(tokens, Wbf, sA + 8192,  sB + 8192,  1, m0, n0, MG, w, l);
  stage(tokens, Wbf, sA + 16384, sB + 16384, 2, m0, n0, MG, w, l);
  asm volatile("s_waitcnt vmcnt(8)" ::: "memory");
  __builtin_amdgcn_s_barrier();
  __builtin_amdgcn_sched_barrier(0);

#pragma unroll 4
  for (int kt = 0; kt < 28; ++kt) {
    const int slot = kt & 3;
    if (kt + 3 < 28) {
      const int s2 = (kt + 3) & 3;
      stage(tokens, Wbf, sA + s2 * 8192, sB + s2 * 8192, kt + 3, m0, n0, MG, w, l);
    }
    const ushort_t* pA = sA + slot * 8192 + aoffb;
    const ushort_t* pB = sB + slot * 8192 + boffb;
    bf16x8 a[8], bv[4];
#pragma unroll
    for (int m = 0; m < 8; ++m) a[m] = *(const bf16x8*)(pA + m * 512);
#pragma unroll
    for (int n = 0; n < 4; ++n) bv[n] = *(const bf16x8*)(pB + n * 512);
    __builtin_amdgcn_s_setprio(1);
#pragma unroll
    for (int m = 0; m < 8; ++m)
#pragma unroll
      for (int n = 0; n < 4; ++n)
        acc[m][n] = __builtin_amdgcn_mfma_f32_16x16x32_bf16(a[m], bv[n], acc[m][n], 0, 0, 0);
    __builtin_amdgcn_s_setprio(0);
    if (kt < 27) {
      // need tile kt+1 landed; allow {kt+2, kt+3} in flight (4 loads each)
      if (kt < 25)       asm volatile("s_waitcnt vmcnt(8)" ::: "memory");
      else if (kt == 25) asm volatile("s_waitcnt vmcnt(4)" ::: "memory");
      else               asm volatile("s_waitcnt vmcnt(0)" ::: "memory");
      __builtin_amdgcn_sched_barrier(0);
      __builtin_amdgcn_s_barrier();
      __builtin_amdgcn_sched_barrier(0);
    }
  }

  // epilogue: D col=lane&15, row=(lane>>4)*4+r; fold SCALE into Q cols (<896)
#pragma unroll
  for (int m = 0; m < 8; ++m) {
#pragma unroll
    for (int n = 0; n < 4; ++n) {
      int gcol = n0 + nw * 64 + n * 16 + lrow;
      float sc = (gcol < C_) ? SCALE : 1.0f;
#pragma unroll
      for (int r = 0; r < 4; ++r) {
        int grow = m0 + mw * 128 + m * 16 + hi * 4 + r;
        if (grow < MG)
          QK[(size_t)grow * CQK + gcol] = f2bf(acc[m][n][r] * sc);
      }
    }
  }
}

// ---------------- kernel 4: per-batch logits + softmax + min (in-register) ----------------
__global__ __launch_bounds__(256) void k_attn2(const ushort_t* __restrict__ QK,
                                               float* __restrict__ fusedg,
                                               int boff) {
  const int bl   = blockIdx.x;
  const int tid  = threadIdx.x;
  const int wid  = tid >> 6;
  const int lane = tid & 63;
  const int lrow = lane & 15;
  const int hi   = lane >> 4;
  const int lk   = hi * 8;
  const f32x4 z4 = {0.f, 0.f, 0.f, 0.f};

  int qrow = wid * 16 + lrow; if (qrow > 48) qrow = 48;
  const ushort_t* Qrow = QK + (size_t)(bl * 49 + qrow) * CQK;

  float fu[16];

  for (int h = 0; h < NH; ++h) {
    f32x4 acc2[4] = {z4, z4, z4, z4};
#pragma unroll
    for (int e = 0; e < 4; ++e) {
      bf16x8 qf = *(const bf16x8*)(Qrow + h * HD + e * 32 + lk);
#pragma unroll
      for (int kt = 0; kt < 4; ++kt) {
        int krow = kt * 16 + lrow; if (krow > 48) krow = 48;
        bf16x8 kf = *(const bf16x8*)(QK + (size_t)(bl * 49 + krow) * CQK
                                     + C_ + h * HD + e * 32 + lk);
        acc2[kt] = __builtin_amdgcn_mfma_f32_16x16x32_bf16(kf, qf, acc2[kt], 0, 0, 0);
      }
    }
    float mx = -1e30f;
#pragma unroll
    for (int kt = 0; kt < 4; ++kt)
#pragma unroll
      for (int r = 0; r < 4; ++r) {
        int k = kt * 16 + hi * 4 + r;
        if (k < N_) mx = fmaxf(mx, acc2[kt][r]);
      }
    mx = fmaxf(mx, __shfl_xor(mx, 16));
    mx = fmaxf(mx, __shfl_xor(mx, 32));
    float ev[16];
    float sum = 0.f;
#pragma unroll
    for (int kt = 0; kt < 4; ++kt)
#pragma unroll
      for (int r = 0; r < 4; ++r) {
        int k = kt * 16 + hi * 4 + r;
        float e = (k < N_) ? __expf(acc2[kt][r] - mx) : 0.f;
        ev[kt * 4 + r] = e;
        sum += e;
      }
    sum += __shfl_xor(sum, 16);
    sum += __shfl_xor(sum, 32);
    float rs = 1.0f / sum;
#pragma unroll
    for (int i = 0; i < 16; ++i) {
      float p = ev[i] * rs;
      fu[i] = (h == 0) ? p : fminf(fu[i], p);
    }
    if (h == NH - 1) {
      int q = wid * 16 + lrow;
      if (q < N_) {
#pragma unroll
        for (int kt = 0; kt < 4; ++kt)
#pragma unroll
          for (int r = 0; r < 4; ++r) {
            int k = kt * 16 + hi * 4 + r;
            if (k < N_)
              fusedg[(size_t)(boff + bl) * NN + q * N_ + k] = fu[kt * 4 + r];
          }
      }
    }
  }
}

// ---------------- kernel 5: select (bottom-2160 mask union) + rollout for all b ----------------
// att[0] computed unmasked here; overwritten by k_fix0 afterwards.
__global__ void k_selroll(const float* __restrict__ fusedg, u32* __restrict__ gmask,
                          float* __restrict__ att) {
  __shared__ u32 v[NN];
  __shared__ u32 lmask[76];
  __shared__ int cnt;
  const int b = blockIdx.x, t = threadIdx.x;
  for (int p = t; p < NN; p += 256)
    v[p] = __builtin_bit_cast(u32, fusedg[(size_t)b * NN + p]);
  for (int p = t; p < 76; p += 256) lmask[p] = 0u;
  __syncthreads();
  u32 u = 0;
  for (int bit = 30; bit >= 0; --bit) {
    u32 cand = u | (1u << bit);
    if (t == 0) cnt = 0;
    __syncthreads();
    int c = 0;
    for (int p = t; p < NN; p += 256) c += (v[p] < cand) ? 1 : 0;
    atomicAdd(&cnt, c);
    __syncthreads();
    if (cnt < KTOP) u = cand;
    __syncthreads();
  }
  for (int p = t; p < NN; p += 256)
    if (p != 0 && v[p] <= u) atomicOr(&lmask[p >> 5], 1u << (p & 31));
  __syncthreads();
  for (int p = t; p < 76; p += 256)
    if (lmask[p]) atomicOr(&gmask[p], lmask[p]);
  // rollout sums from the (unmasked) values in LDS — valid for b>0
  if (t < N_) {
    float rs = 0.f, cs = 0.f;
    for (int m = 0; m < N_; ++m) {
      rs += __builtin_bit_cast(float, v[t * N_ + m]);
      cs += __builtin_bit_cast(float, v[m * N_ + t]);
    }
    att[b * N_ + t] = (cs + 1.0f) / (49.0f * (rs + 1.0f));
  }
}

// ---------------- kernel 6: batch-0 fixup: apply union mask, redo rollout ----------------
__global__ void k_fix0(const float* __restrict__ fusedg, const u32* __restrict__ gmask,
                       float* __restrict__ att) {
  __shared__ float fl[NN];
  const int t = threadIdx.x;
  for (int p = t; p < NN; p += 256) {
    float vv = fusedg[p];
    if ((gmask[p >> 5] >> (p & 31)) & 1u) vv = 0.f;
    fl[p] = vv;
  }
  __syncthreads();
  if (t < N_) {
    float rs = 0.f, cs = 0.f;
    for (int m = 0; m < N_; ++m) { rs += fl[t * N_ + m]; cs += fl[m * N_ + t]; }
    att[t] = (cs + 1.0f) / (49.0f * (rs + 1.0f));
  }
}

// ---------------- kernel 7: rx = x * (1 + att[b,n]) ----------------
__global__ void k_rx(const float* __restrict__ x, const float* __restrict__ att,
                     float* __restrict__ out) {
  const long total4 = (long)B_ * C_ * N_ / 4;
  for (long g = (long)blockIdx.x * 256 + threadIdx.x; g < total4; g += (long)gridDim.x * 256) {
    long e0 = g * 4;
    int b = (int)(e0 / (C_ * N_));
    int r = (int)(e0 - (long)b * (C_ * N_));
    int n = r % N_;
    const float4 xv = ((const float4*)x)[g];
    const float* ab = att + b * N_;
    float a0 = ab[n];
    int n1 = n + 1;  if (n1 == N_) n1 = 0;  float a1 = ab[n1];
    int n2 = n1 + 1; if (n2 == N_) n2 = 0;  float a2 = ab[n2];
    int n3 = n2 + 1; if (n3 == N_) n3 = 0;  float a3 = ab[n3];
    float4 o;
    o.x = xv.x * (1.f + a0); o.y = xv.y * (1.f + a1);
    o.z = xv.z * (1.f + a2); o.w = xv.w * (1.f + a3);
    ((float4*)out)[g] = o;
  }
}

extern "C" void kernel_launch(void* const* d_in, const int* in_sizes, int n_in,
                              void* d_out, int out_size, void* d_ws, size_t ws_size,
                              hipStream_t stream) {
  const float* x = (const float*)d_in[0];
  const float* W = (const float*)d_in[1];
  float* out = (float*)d_out;
  char* ws = (char*)d_ws;

  // choose group size G (batches per pass) by workspace capacity
  const size_t fixed = 9834496 /*fused*/ + 200704 /*att*/ + 3211264 /*Wbf*/ + 1024 /*gmask*/;
  int G = 32;
  const int cands[6] = {1024, 512, 256, 128, 64, 32};
  for (int i = 0; i < 6; ++i) {
    if (fixed + (size_t)cands[i] * 49 * CQK * 2 <= ws_size) { G = cands[i]; break; }
  }

  const size_t qkbytes = (size_t)G * 49 * CQK * 2;
  ushort_t* QKg   = (ushort_t*)ws;
  float*    fused = (float*)(ws + qkbytes);
  float*    att   = (float*)(ws + qkbytes + 9834496);
  ushort_t* Wbf   = (ushort_t*)(ws + qkbytes + 9834496 + 200704);
  u32*      gmask = (u32*)(ws + qkbytes + 9834496 + 200704 + 3211264);
  ushort_t* tokens = (ushort_t*)d_out;   // scratch; d_out fully rewritten by k_rx

  hipMemsetAsync(gmask, 0, 76 * sizeof(u32), stream);
  k_convW<<<(CQK * C_ + 255) / 256, 256, 0, stream>>>(W, Wbf);

  hipFuncSetAttribute((const void*)k_gemm, hipFuncAttributeMaxDynamicSharedMemorySize, GEMM_LDS);

  const int ngroups = B_ / G;
  for (int g = 0; g < ngroups; ++g) {
    const int boff = g * G;
    const int MG = G * 49;
    const int mtc = (MG + 255) / 256;
    k_tr<<<G * 14, 256, 0, stream>>>(x, tokens, boff);
    k_gemm<<<mtc * 7, 512, GEMM_LDS, stream>>>(tokens, Wbf, QKg, MG, mtc);
    k_attn2<<<G, 256, 0, stream>>>(QKg, fused, boff);
  }

  k_selroll<<<B_, 256, 0, stream>>>(fused, gmask, att);
  k_fix0<<<1, 256, 0, stream>>>(fused, gmask, att);
  k_rx<<<2048, 256, 0, stream>>>(x, att, out);
}

// Round 6
// 488.818 us; speedup vs baseline: 2.2386x; 1.0692x over previous
//
#include <hip/hip_runtime.h>
#include <hip/hip_bf16.h>

#define B_    1024
#define C_    896
#define N_    49
#define NN    2401
#define HD    128
#define NH    7
#define CQK   1792      // q,k rows of W (V never used)
#define KTOP  2160      // int(2401*0.9)
#define SCALE 0.08838834764831845f  // 128^-0.5

typedef unsigned short ushort_t;
typedef unsigned int u32;
typedef short bf16x8 __attribute__((ext_vector_type(8)));
typedef float f32x4  __attribute__((ext_vector_type(4)));

__device__ __forceinline__ ushort_t f2bf(float f) {
  u32 u = __builtin_bit_cast(u32, f);
  u += 0x7FFFu + ((u >> 16) & 1u);          // RNE
  return (ushort_t)(u >> 16);
}

__device__ __forceinline__ void gload16(const ushort_t* g, ushort_t* l) {
  __builtin_amdgcn_global_load_lds((const __attribute__((address_space(1))) u32*)g,
                                   (__attribute__((address_space(3))) u32*)l, 16, 0, 0);
}

#define BAR()   __builtin_amdgcn_s_barrier()
#define LGKM0() do { asm volatile("s_waitcnt lgkmcnt(0)" ::: "memory"); \
                     __builtin_amdgcn_sched_barrier(0); } while (0)
#define VMC(n)  do { asm volatile("s_waitcnt vmcnt(" #n ")" ::: "memory"); \
                     __builtin_amdgcn_sched_barrier(0); } while (0)

// ---------------- kernel 1: W (first 1792 rows) -> bf16 ----------------
__global__ void k_convW(const float* __restrict__ W, ushort_t* __restrict__ Wbf) {
  int i = blockIdx.x * 256 + threadIdx.x;
  if (i < CQK * C_) Wbf[i] = f2bf(W[i]);
}

// ---------------- kernel 2: transpose x -> tokens bf16 [MG][896] ----------------
__global__ __launch_bounds__(256) void k_tr(const float* __restrict__ x,
                                            ushort_t* __restrict__ tokens,
                                            int boff) {
  __shared__ ushort_t T2[49][76];   // 152 B rows -> 2-way banks on b128 reads
  const int bid = blockIdx.x;
  const int bl  = bid / 14;            // local batch
  const int cg  = bid % 14;            // c-group (64 channels)
  const float* xb = x + (size_t)(boff + bl) * (C_ * N_) + (size_t)cg * 64 * N_;
  for (int idx = threadIdx.x; idx < 64 * 49; idx += 256) {
    int ci = idx / 49, n = idx - ci * 49;
    T2[n][ci] = f2bf(xb[ci * 49 + n]);
  }
  __syncthreads();
  ushort_t* tb = tokens + (size_t)(bl * 49) * C_ + cg * 64;
  for (int idx = threadIdx.x; idx < 49 * 8; idx += 256) {
    int n = idx >> 3, ch = idx & 7;
    *(bf16x8*)(tb + (size_t)n * C_ + ch * 8) = *(const bf16x8*)&T2[n][ch * 8];
  }
}

// ---------------- kernel 3: GEMM QK = tokens * Wbf^T, 8-phase schedule ----------------
// 256x256 tile, BK=64, 8 waves (wm=w&1 row-half, wn=w>>1 col-quarter), wave tile 128x64.
// LDS: sA[2 slot][2 half][128 rows][64 el] + sB same = 128 KB. slot = kt&1.
// Swizzle: 16B-slot phys = logical ^ (row&7); applied on global src (linear LDS dest)
// and on ds_read addresses.
#define GEMM_LDS 131072

__global__ __launch_bounds__(512, 2) void k_gemm(const ushort_t* __restrict__ tokens,
                                                 const ushort_t* __restrict__ Wbf,
                                                 ushort_t* __restrict__ QK,
                                                 int MG) {
  extern __shared__ ushort_t gsm[];
  ushort_t* sA = gsm;            // 32768 el
  ushort_t* sB = gsm + 32768;

  // bijective XCD-chunk swizzle (m204)
  const int nwg = gridDim.x;
  const int q8 = nwg >> 3, r8 = nwg & 7;
  const int xcd = blockIdx.x & 7, idx8 = blockIdx.x >> 3;
  const int tile = (xcd < r8 ? xcd * (q8 + 1) : r8 * (q8 + 1) + (xcd - r8) * q8) + idx8;

  const int mt = tile / 7, nt = tile - mt * 7;
  const int m0 = mt * 256, n0 = nt * 256;

  const int t = threadIdx.x;
  const int w = t >> 6, l = t & 63;
  const int lrow = l & 15, hi = l >> 4;
  const int wm = w & 1, wn = w >> 1;   // wn 0..3

  // stage-side precompute: thread t covers rows (j*64 + t>>3), 16B piece (t&7)
  const int srow = t >> 3;                          // 0..63
  const int scol = 8 * ((t & 7) ^ (srow & 7));      // pre-swizzled source col (els)
  ushort_t* ldsA = sA + t * 8;
  ushort_t* ldsB = sB + t * 8;
  const ushort_t* wSrc = Wbf + (size_t)(n0 + srow) * C_ + scol;

  // frag-side precompute: phys slot = (kh*4+hi) ^ (lrow&7)  (row%8 == lrow%8)
  const int ph0 = 8 * (hi ^ (lrow & 7));
  const int ph1 = 8 * ((4 + hi) ^ (lrow & 7));
  const ushort_t* aBase = sA + wm * 8192 + lrow * 64;
  const ushort_t* bBase = sB + (wn >> 1) * 8192 + ((wn & 1) * 64 + lrow) * 64;

  f32x4 acc[8][4];
#pragma unroll
  for (int m = 0; m < 8; ++m)
#pragma unroll
    for (int n = 0; n < 4; ++n) acc[m][n] = (f32x4){0.f, 0.f, 0.f, 0.f};

  bf16x8 a[4][2], b[4][2];

  auto STA = [&](int kt, int half) {
    const int slot = kt & 1;
#pragma unroll
    for (int j = 0; j < 2; ++j) {
      int gr = m0 + half * 128 + j * 64 + srow;
      if (gr >= MG) gr = MG - 1;
      gload16(tokens + (size_t)gr * C_ + kt * 64 + scol,
              ldsA + slot * 16384 + half * 8192 + j * 4096);
    }
  };
  auto STB = [&](int kt, int half) {
    const int slot = kt & 1;
#pragma unroll
    for (int j = 0; j < 2; ++j)
      gload16(wSrc + (size_t)(half * 128 + j * 64) * C_ + kt * 64,
              ldsB + slot * 16384 + half * 8192 + j * 4096);
  };
  auto LDA = [&](int slot, int mq) {
#pragma unroll
    for (int mm = 0; mm < 4; ++mm) {
      const ushort_t* p = aBase + slot * 16384 + (mq * 4 + mm) * 1024;
      a[mm][0] = *(const bf16x8*)(p + ph0);
      a[mm][1] = *(const bf16x8*)(p + ph1);
    }
  };
  auto LDB = [&](int slot, int np) {
#pragma unroll
    for (int nn = 0; nn < 2; ++nn) {
      const ushort_t* p = bBase + slot * 16384 + (np * 2 + nn) * 1024;
      b[np * 2 + nn][0] = *(const bf16x8*)(p + ph0);
      b[np * 2 + nn][1] = *(const bf16x8*)(p + ph1);
    }
  };
  auto MM = [&](int mq, int np) {
    __builtin_amdgcn_s_setprio(1);
#pragma unroll
    for (int mm = 0; mm < 4; ++mm)
#pragma unroll
      for (int nn = 0; nn < 2; ++nn) {
        const int n = np * 2 + nn;
#pragma unroll
        for (int kh = 0; kh < 2; ++kh)
          acc[mq * 4 + mm][n] =
              __builtin_amdgcn_mfma_f32_16x16x32_bf16(a[mm][kh], b[n][kh],
                                                      acc[mq * 4 + mm][n], 0, 0, 0);
      }
    __builtin_amdgcn_s_setprio(0);
  };

  // prologue: k0 full (8 ops oldest) + k1.Bh0,Bh1,Ah0 (6 newest in flight)
  STA(0, 0); STA(0, 1); STB(0, 0); STB(0, 1);
  STB(1, 0); STB(1, 1); STA(1, 0);
  VMC(6);
  BAR();

#pragma unroll 1
  for (int it = 0; it < 7; ++it) {
    const int k1 = 2 * it + 1, k2 = 2 * it + 2, k3 = 2 * it + 3;
    const bool st = (it < 6);
    // ---- K-tile k0 (slot 0) ----
    // P1
    LDA(0, 0); LDB(0, 0);
    STA(k1, 1);
    BAR(); LGKM0(); MM(0, 0); BAR();
    // P2
    LDB(0, 1);
    BAR(); LGKM0(); MM(0, 1); BAR();
    // P3
    LDA(0, 1);
    if (st) STB(k2, 0);
    BAR(); LGKM0(); MM(1, 1); BAR();
    // P4
    if (st) STB(k2, 1);
    BAR(); MM(1, 0);
    if (st) { VMC(4); } else { VMC(0); }
    BAR();
    // ---- K-tile k1 (slot 1) ----
    // P5
    LDA(1, 0); LDB(1, 0);
    if (st) STA(k2, 0);
    BAR(); LGKM0(); MM(0, 0); BAR();
    // P6
    LDB(1, 1);
    if (st) STA(k2, 1);
    BAR(); LGKM0(); MM(0, 1); BAR();
    // P7
    LDA(1, 1);
    if (st) STB(k3, 0);
    BAR(); LGKM0(); MM(1, 1); BAR();
    // P8
    if (st) { STB(k3, 1); STA(k3, 0); }
    BAR(); MM(1, 0);
    if (st) { VMC(6); } else { VMC(0); }
    BAR();
  }

  // epilogue: D col=lane&15, row=(lane>>4)*4+r; fold SCALE into Q cols (<896)
#pragma unroll
  for (int m = 0; m < 8; ++m) {
#pragma unroll
    for (int n = 0; n < 4; ++n) {
      int gcol = n0 + wn * 64 + n * 16 + lrow;
      float sc = (gcol < C_) ? SCALE : 1.0f;
#pragma unroll
      for (int r = 0; r < 4; ++r) {
        int grow = m0 + wm * 128 + m * 16 + hi * 4 + r;
        if (grow < MG)
          QK[(size_t)grow * CQK + gcol] = f2bf(acc[m][n][r] * sc);
      }
    }
  }
}

// ---------------- kernel 4: logits + softmax + min, one WAVE per batch ----------------
__global__ __launch_bounds__(256) void k_attn2(const ushort_t* __restrict__ QK,
                                               float* __restrict__ fusedg,
                                               int boff) {
  const int tid  = threadIdx.x;
  const int wid  = tid >> 6;
  const int lane = tid & 63;
  const int lrow = lane & 15;
  const int hi   = lane >> 4;
  const int lk   = hi * 8;
  const int bl   = blockIdx.x * 4 + wid;
  const f32x4 z4 = {0.f, 0.f, 0.f, 0.f};

  const ushort_t* Qb = QK + (size_t)bl * 49 * CQK;          // + qrow*CQK + h*HD
  const ushort_t* Kb = Qb + C_;

  int qr[4], kr[4];
#pragma unroll
  for (int i = 0; i < 4; ++i) {
    int r = i * 16 + lrow; if (r > 48) r = 48;
    qr[i] = r; kr[i] = r;
  }

  float fu[4][16];

  for (int h = 0; h < NH; ++h) {
    f32x4 acc[4][4];   // [qt][kt]
#pragma unroll
    for (int qt = 0; qt < 4; ++qt)
#pragma unroll
      for (int kt = 0; kt < 4; ++kt) acc[qt][kt] = z4;

#pragma unroll
    for (int e = 0; e < 4; ++e) {
      bf16x8 kf[4], qf[4];
#pragma unroll
      for (int kt = 0; kt < 4; ++kt)
        kf[kt] = *(const bf16x8*)(Kb + (size_t)kr[kt] * CQK + h * HD + e * 32 + lk);
#pragma unroll
      for (int qt = 0; qt < 4; ++qt)
        qf[qt] = *(const bf16x8*)(Qb + (size_t)qr[qt] * CQK + h * HD + e * 32 + lk);
#pragma unroll
      for (int qt = 0; qt < 4; ++qt)
#pragma unroll
        for (int kt = 0; kt < 4; ++kt)
          acc[qt][kt] = __builtin_amdgcn_mfma_f32_16x16x32_bf16(kf[kt], qf[qt],
                                                                acc[qt][kt], 0, 0, 0);
    }

#pragma unroll
    for (int qt = 0; qt < 4; ++qt) {
      float mx = -1e30f;
#pragma unroll
      for (int kt = 0; kt < 4; ++kt)
#pragma unroll
        for (int r = 0; r < 4; ++r) {
          int k = kt * 16 + hi * 4 + r;
          if (k < N_) mx = fmaxf(mx, acc[qt][kt][r]);
        }
      mx = fmaxf(mx, __shfl_xor(mx, 16));
      mx = fmaxf(mx, __shfl_xor(mx, 32));
      float ev[16];
      float sum = 0.f;
#pragma unroll
      for (int kt = 0; kt < 4; ++kt)
#pragma unroll
        for (int r = 0; r < 4; ++r) {
          int k = kt * 16 + hi * 4 + r;
          float e = (k < N_) ? __expf(acc[qt][kt][r] - mx) : 0.f;
          ev[kt * 4 + r] = e;
          sum += e;
        }
      sum += __shfl_xor(sum, 16);
      sum += __shfl_xor(sum, 32);
      float rs = 1.0f / sum;
#pragma unroll
      for (int i = 0; i < 16; ++i) {
        float p = ev[i] * rs;
        fu[qt][i] = (h == 0) ? p : fminf(fu[qt][i], p);
      }
    }
  }

#pragma unroll
  for (int qt = 0; qt < 4; ++qt) {
    int q = qt * 16 + lrow;
    if (q < N_) {
#pragma unroll
      for (int kt = 0; kt < 4; ++kt)
#pragma unroll
        for (int r = 0; r < 4; ++r) {
          int k = kt * 16 + hi * 4 + r;
          if (k < N_)
            fusedg[(size_t)(boff + bl) * NN + q * N_ + k] = fu[qt][kt * 4 + r];
        }
    }
  }
}

// ---------------- kernel 5: select (bottom-2160 mask union) + rollout ----------------
__global__ void k_selroll(const float* __restrict__ fusedg, u32* __restrict__ gmask,
                          float* __restrict__ att) {
  __shared__ u32 v[NN];
  __shared__ u32 lmask[76];
  __shared__ int cnt;
  const int b = blockIdx.x, t = threadIdx.x;
  for (int p = t; p < NN; p += 256)
    v[p] = __builtin_bit_cast(u32, fusedg[(size_t)b * NN + p]);
  for (int p = t; p < 76; p += 256) lmask[p] = 0u;
  __syncthreads();
  u32 u = 0;
  for (int bit = 30; bit >= 0; --bit) {
    u32 cand = u | (1u << bit);
    if (t == 0) cnt = 0;
    __syncthreads();
    int c = 0;
    for (int p = t; p < NN; p += 256) c += (v[p] < cand) ? 1 : 0;
    atomicAdd(&cnt, c);
    __syncthreads();
    if (cnt < KTOP) u = cand;
    __syncthreads();
  }
  for (int p = t; p < NN; p += 256)
    if (p != 0 && v[p] <= u) atomicOr(&lmask[p >> 5], 1u << (p & 31));
  __syncthreads();
  for (int p = t; p < 76; p += 256)
    if (lmask[p]) atomicOr(&gmask[p], lmask[p]);
  // rollout from the (unmasked) values — valid for b>0; b=0 fixed by k_fix0
  if (t < N_) {
    float rs = 0.f, cs = 0.f;
    for (int m = 0; m < N_; ++m) {
      rs += __builtin_bit_cast(float, v[t * N_ + m]);
      cs += __builtin_bit_cast(float, v[m * N_ + t]);
    }
    att[b * N_ + t] = (cs + 1.0f) / (49.0f * (rs + 1.0f));
  }
}

// ---------------- kernel 6: batch-0 fixup ----------------
__global__ void k_fix0(const float* __restrict__ fusedg, const u32* __restrict__ gmask,
                       float* __restrict__ att) {
  __shared__ float fl[NN];
  const int t = threadIdx.x;
  for (int p = t; p < NN; p += 256) {
    float vv = fusedg[p];
    if ((gmask[p >> 5] >> (p & 31)) & 1u) vv = 0.f;
    fl[p] = vv;
  }
  __syncthreads();
  if (t < N_) {
    float rs = 0.f, cs = 0.f;
    for (int m = 0; m < N_; ++m) { rs += fl[t * N_ + m]; cs += fl[m * N_ + t]; }
    att[t] = (cs + 1.0f) / (49.0f * (rs + 1.0f));
  }
}

// ---------------- kernel 7: rx = x * (1 + att[b,n]), 32-bit index math ----------------
__global__ void k_rx(const float* __restrict__ x, const float* __restrict__ att,
                     float* __restrict__ out) {
  const int total4 = B_ * C_ * N_ / 4;   // 11,239,424 (fits int)
  for (int g = blockIdx.x * 256 + threadIdx.x; g < total4; g += gridDim.x * 256) {
    u32 e0 = (u32)g * 4u;
    u32 b = e0 / (u32)(C_ * N_);
    u32 r = e0 - b * (u32)(C_ * N_);
    u32 n = r % (u32)N_;
    const float4 xv = ((const float4*)x)[g];
    const float* ab = att + b * N_;
    float a0 = ab[n];
    u32 n1 = n + 1;  if (n1 == N_) n1 = 0;  float a1 = ab[n1];
    u32 n2 = n1 + 1; if (n2 == N_) n2 = 0;  float a2 = ab[n2];
    u32 n3 = n2 + 1; if (n3 == N_) n3 = 0;  float a3 = ab[n3];
    float4 o;
    o.x = xv.x * (1.f + a0); o.y = xv.y * (1.f + a1);
    o.z = xv.z * (1.f + a2); o.w = xv.w * (1.f + a3);
    ((float4*)out)[g] = o;
  }
}

extern "C" void kernel_launch(void* const* d_in, const int* in_sizes, int n_in,
                              void* d_out, int out_size, void* d_ws, size_t ws_size,
                              hipStream_t stream) {
  const float* x = (const float*)d_in[0];
  const float* W = (const float*)d_in[1];
  float* out = (float*)d_out;
  char* ws = (char*)d_ws;

  // group size G (batches per pass): multiples of 256 so MG % 256 == 0
  const size_t fixed = 9834496 /*fused*/ + 200704 /*att*/ + 3211264 /*Wbf*/ + 1024 /*gmask*/;
  int G = 256;
  const int cands[3] = {1024, 512, 256};
  for (int i = 0; i < 3; ++i) {
    if (fixed + (size_t)cands[i] * 49 * CQK * 2 <= ws_size) { G = cands[i]; break; }
  }

  const size_t qkbytes = (size_t)G * 49 * CQK * 2;
  ushort_t* QKg   = (ushort_t*)ws;
  float*    fused = (float*)(ws + qkbytes);
  float*    att   = (float*)(ws + qkbytes + 9834496);
  ushort_t* Wbf   = (ushort_t*)(ws + qkbytes + 9834496 + 200704);
  u32*      gmask = (u32*)(ws + qkbytes + 9834496 + 200704 + 3211264);
  ushort_t* tokens = (ushort_t*)d_out;   // scratch; d_out fully rewritten by k_rx

  hipMemsetAsync(gmask, 0, 76 * sizeof(u32), stream);
  k_convW<<<(CQK * C_ + 255) / 256, 256, 0, stream>>>(W, Wbf);

  hipFuncSetAttribute((const void*)k_gemm, hipFuncAttributeMaxDynamicSharedMemorySize, GEMM_LDS);

  const int ngroups = B_ / G;
  for (int g = 0; g < ngroups; ++g) {
    const int boff = g * G;
    const int MG = G * 49;
    const int mtc = MG / 256;
    k_tr<<<G * 14, 256, 0, stream>>>(x, tokens, boff);
    k_gemm<<<mtc * 7, 512, GEMM_LDS, stream>>>(tokens, Wbf, QKg, MG);
    k_attn2<<<G / 4, 256, 0, stream>>>(QKg, fused, boff);
  }

  k_selroll<<<B_, 256, 0, stream>>>(fused, gmask, att);
  k_fix0<<<1, 256, 0, stream>>>(fused, gmask, att);
  k_rx<<<2048, 256, 0, stream>>>(x, att, out);
}